// Round 10
// baseline (209.104 us; speedup 1.0000x reference)
//
#include <hip/hip_runtime.h>
#include <hip/hip_bf16.h>
#include <cfloat>

#define NN 4096
#define DD 256
#define KTOP 10
#define MTOP 5
#define MUSEL 2048
#define NCLS 31

typedef unsigned long long u64;
typedef unsigned int u32;
typedef __attribute__((ext_vector_type(8))) short short8;   // 8 bf16 (4 VGPRs)
typedef __attribute__((ext_vector_type(4))) float f32x4;    // MFMA acc

static __device__ __forceinline__ unsigned short f2bf(float x) {
    u32 u = __float_as_uint(x);
    u32 r = (u + 0x7FFFu + ((u >> 16) & 1u)) >> 16;   // RNE, no NaN inputs here
    return (unsigned short)r;
}
static __device__ __forceinline__ float bf2f(unsigned short h) {
    return __uint_as_float((u32)h << 16);
}

// ---- DPP wave reductions (canonical row_shr/row_bcast sequence, result lane63,
// readlane 63 -> wave-uniform). Validated on HW in rounds 4/8 (passing runs).
template <int C>
static __device__ __forceinline__ u32 dpp_keep(u32 x) {   // invalid lanes keep old
    return (u32)__builtin_amdgcn_update_dpp((int)x, (int)x, C, 0xF, 0xF, false);
}
template <int C>
static __device__ __forceinline__ u32 dpp_zero(u32 x) {   // invalid lanes -> 0
    return (u32)__builtin_amdgcn_update_dpp(0, (int)x, C, 0xF, 0xF, true);
}
static __device__ __forceinline__ u32 wred_max(u32 x) {
#define S(C) { u32 t = dpp_keep<C>(x); x = t > x ? t : x; }
    S(0x111) S(0x112) S(0x114) S(0x118) S(0x142) S(0x143)
#undef S
    return (u32)__builtin_amdgcn_readlane((int)x, 63);
}
static __device__ __forceinline__ u32 wred_sum_u32(u32 x) {
#define S(C) { u32 t = dpp_zero<C>(x); x += t; }
    S(0x111) S(0x112) S(0x114) S(0x118) S(0x142) S(0x143)
#undef S
    return (u32)__builtin_amdgcn_readlane((int)x, 63);
}
static __device__ __forceinline__ float wred_sumf(float x) {
#define S(C) { u32 t = dpp_zero<C>(__float_as_uint(x)); x += __uint_as_float(t); }
    S(0x111) S(0x112) S(0x114) S(0x118) S(0x142) S(0x143)
#undef S
    return __uint_as_float((u32)__builtin_amdgcn_readlane((int)__float_as_uint(x), 63));
}

// ---- merge (value,count) pairs from LDS: descending distinct-value scan until
// cumulative count crosses `need`. Returns exact threshold t + boundary count bn.
// If pairs exhaust first (stream smaller than need): t=0, bn=0 ("take all").
// Run by ONE full wave; results wave-uniform.
static __device__ __forceinline__ void merge_pairs(const u32* pairs, int n, u32 need,
                                                   u32& t, u32& bn, int lane) {
    u32 val = (lane < n) ? pairs[lane * 2] : 0u;
    u32 cnt = (lane < n) ? pairs[lane * 2 + 1] : 0u;
    t = 0u; bn = 0u;
    for (int k = 0; k < 10; ++k) {
        if (need == 0u) break;                 // wave-uniform
        u32 m = wred_max(val);
        if (m == 0u) break;                    // exhausted -> take-all semantics
        u32 c = wred_sum_u32(val == m ? cnt : 0u);
        if (c >= need) { t = m; bn = need; break; }
        need -= c;
        if (val == m) val = 0u;
    }
}

// ---------------- kernel 0: fused fp32->bf16 hi/lo planes + row sq norms -----
__global__ __launch_bounds__(256) void prep_kernel(const float* __restrict__ src,
                                                   const float* __restrict__ tgt,
                                                   unsigned short* __restrict__ src_hi,
                                                   unsigned short* __restrict__ src_lo,
                                                   unsigned short* __restrict__ tgt_hi,
                                                   unsigned short* __restrict__ tgt_lo,
                                                   float* __restrict__ sq_s,
                                                   float* __restrict__ sq_t) {
    int r = blockIdx.x;                      // 0..2N-1
    bool isT = r >= NN;
    int rr = isT ? r - NN : r;
    const float* base = (isT ? tgt : src) + (size_t)rr * DD;
    float x = base[threadIdx.x];
    unsigned short h = f2bf(x);
    unsigned short l = f2bf(x - bf2f(h));
    size_t o = (size_t)rr * DD + threadIdx.x;
    if (isT) { tgt_hi[o] = h; tgt_lo[o] = l; } else { src_hi[o] = h; src_lo[o] = l; }
    float p = x * x;
    for (int off = 32; off > 0; off >>= 1) p += __shfl_down(p, off);
    __shared__ float red[4];
    int wid = threadIdx.x >> 6, lane = threadIdx.x & 63;
    if (lane == 0) red[wid] = p;
    __syncthreads();
    if (threadIdx.x == 0) {
        float s = red[0] + red[1] + red[2] + red[3];
        if (isT) sq_t[rr] = s; else sq_s[rr] = s;
    }
}

// ---------------- kernel 2: bf16 MFMA GEMM, 4-plane staging + double buffer --
// dot = hiT.hiS + hiT.loS + loT.hiS. Stage all 4 unique planes per 32-wide
// K-slice; prefetch slice t+1 into buf^1 before consuming buf (T3-minimum):
// staging latency hides under the 48 MFMAs. 64KB LDS -> 2 blocks/CU.
static __device__ __forceinline__ void gload(const unsigned short* g, short* l) {
    __builtin_amdgcn_global_load_lds((const __attribute__((address_space(1))) void*)g,
                                     (__attribute__((address_space(3))) void*)l, 16, 0, 0);
}

__global__ __launch_bounds__(256) void gemm_mfma_kernel(
        const unsigned short* __restrict__ tgt_hi, const unsigned short* __restrict__ tgt_lo,
        const unsigned short* __restrict__ src_hi, const unsigned short* __restrict__ src_lo,
        const float* __restrict__ sq_s, const float* __restrict__ sq_t,
        float* __restrict__ simT) {
    __shared__ short Ahi[2][128 * 32];   // tgt_hi tile [row j'][k], 64B rows
    __shared__ short Alo[2][128 * 32];
    __shared__ short Bhi[2][128 * 32];   // src_hi tile [row i'][k]
    __shared__ short Blo[2][128 * 32];
    int tid = threadIdx.x;
    int wid = tid >> 6, lane = tid & 63;
    // bijective XCD swizzle (1024 blocks % 8 == 0)
    int lin = blockIdx.x;
    int wg = (lin & 7) * 128 + (lin >> 3);
    int i0 = (wg & 31) * 128;
    int j0 = (wg >> 5) * 128;
    int wr = wid >> 1, wc = wid & 1;

    f32x4 acc[4][4];
#pragma unroll
    for (int m = 0; m < 4; ++m)
#pragma unroll
        for (int n = 0; n < 4; ++n) acc[m][n] = (f32x4){0.f, 0.f, 0.f, 0.f};

    int srow = wid * 32 + (lane >> 2);    // wave covers tile rows [wid*32, wid*32+32)
    int skoff = (lane & 3) * 8;
    int fr = lane & 15;
    int kq = (lane >> 4) * 8;

#define STAGE_SLICE(kk, bb)                                                      \
    {                                                                            \
        _Pragma("unroll")                                                        \
        for (int r = 0; r < 2; ++r) {                                            \
            int row = srow + r * 16;                                             \
            size_t goA = (size_t)(j0 + row) * DD + (kk) + skoff;                 \
            size_t goB = (size_t)(i0 + row) * DD + (kk) + skoff;                 \
            int ldo = (wid * 2 + r) * 512;                                       \
            gload(tgt_hi + goA, Ahi[bb] + ldo);                                  \
            gload(tgt_lo + goA, Alo[bb] + ldo);                                  \
            gload(src_hi + goB, Bhi[bb] + ldo);                                  \
            gload(src_lo + goB, Blo[bb] + ldo);                                  \
        }                                                                        \
    }

    STAGE_SLICE(0, 0);
    __syncthreads();
    int buf = 0;
    for (int t = 0; t < 8; ++t) {
        if (t < 7) STAGE_SLICE((t + 1) * 32, buf ^ 1);
        short8 ah[4], bh[4], bl[4], al[4];
#pragma unroll
        for (int m = 0; m < 4; ++m) {
            int ra = (wr * 64 + m * 16 + fr) * 32 + kq;
            int rb = (wc * 64 + m * 16 + fr) * 32 + kq;
            ah[m] = *(const short8*)(Ahi[buf] + ra);
            bh[m] = *(const short8*)(Bhi[buf] + rb);
        }
#pragma unroll
        for (int m = 0; m < 4; ++m)
#pragma unroll
            for (int n = 0; n < 4; ++n)
                acc[m][n] = __builtin_amdgcn_mfma_f32_16x16x32_bf16(ah[m], bh[n], acc[m][n], 0, 0, 0);
#pragma unroll
        for (int m = 0; m < 4; ++m)
            bl[m] = *(const short8*)(Blo[buf] + (wc * 64 + m * 16 + fr) * 32 + kq);
#pragma unroll
        for (int m = 0; m < 4; ++m)
#pragma unroll
            for (int n = 0; n < 4; ++n)
                acc[m][n] = __builtin_amdgcn_mfma_f32_16x16x32_bf16(ah[m], bl[n], acc[m][n], 0, 0, 0);
#pragma unroll
        for (int m = 0; m < 4; ++m)
            al[m] = *(const short8*)(Alo[buf] + (wr * 64 + m * 16 + fr) * 32 + kq);
#pragma unroll
        for (int m = 0; m < 4; ++m)
#pragma unroll
            for (int n = 0; n < 4; ++n)
                acc[m][n] = __builtin_amdgcn_mfma_f32_16x16x32_bf16(al[m], bh[n], acc[m][n], 0, 0, 0);
        __syncthreads();     // drains prefetch vmcnt + protects buf reuse
        buf ^= 1;
    }
#undef STAGE_SLICE

    int fq = lane >> 4;
#pragma unroll
    for (int m = 0; m < 4; ++m) {
#pragma unroll
        for (int n = 0; n < 4; ++n) {
            int i = i0 + wc * 64 + n * 16 + fr;
            float ss = sq_s[i];
#pragma unroll
            for (int r = 0; r < 4; ++r) {
                int j = j0 + wr * 64 + m * 16 + fq * 4 + r;
                float d2 = fmaxf(ss + sq_t[j] - 2.0f * acc[m][n][r], 0.0f);
                simT[(size_t)j * NN + i] = 1.0f / (sqrtf(d2) + 1.0f);
            }
        }
    }
}

// ---------------- kernel 3: percol via wave-local tournament extraction ------
// 1 column per 256-thr block (4 waves, 16 vals/thread). Each wave extracts its
// top-k DISTINCT (value,count) pairs in pure VALU/DPP (no LDS, no barriers);
// wave0 merges 4x10 pairs -> exact v10 threshold + boundary count (identical
// semantics to the proven radix path). 8 barriers/block vs 19.
__global__ __launch_bounds__(256) void percol_kernel(const float* __restrict__ simT,
                                                     const int* __restrict__ labels,
                                                     int* __restrict__ assigned,
                                                     float* __restrict__ score) {
    __shared__ u32 pairs1[4][KTOP][2];
    __shared__ u32 pairs2[4][MTOP][2];
    __shared__ u32 pairs3[4][MTOP][2];
    __shared__ u32 votebin[32];
    __shared__ u32 eqlist[64];
    __shared__ u32 s_eqcnt;
    __shared__ u32 s_v10, s_bneed;
    __shared__ u32 s_t2, s_b2, s_t3, s_b3;
    __shared__ float sred2[4], sred3[4];
    int tid = threadIdx.x, lane = tid & 63, wid = tid >> 6;
    int j = blockIdx.x;

    float v[16];
    u32 labp[4];
    {
        const float4* pA = (const float4*)(simT + (size_t)j * NN + tid * 16);
        const int4*  pL = (const int4*)(labels + tid * 16);
#pragma unroll
        for (int q = 0; q < 4; ++q) {
            float4 a = pA[q];
            v[q * 4 + 0] = a.x; v[q * 4 + 1] = a.y; v[q * 4 + 2] = a.z; v[q * 4 + 3] = a.w;
            int4 l = pL[q];
            labp[q] = (u32)l.x | ((u32)l.y << 8) | ((u32)l.z << 16) | ((u32)l.w << 24);
        }
    }
#define LAB(r) ((int)((labp[(r) >> 2] >> (((r) & 3) * 8)) & 0xFFu))
    if (tid < 32) votebin[tid] = 0u;
    if (tid == 0) s_eqcnt = 0u;

    // ---- phase 1: per-wave top-10 (value,count) extraction ----
    {
        u32 thr = ~0u, need = KTOP;
#pragma unroll
        for (int k = 0; k < KTOP; ++k) {
            u32 lm = 0u;
            if (need) {
#pragma unroll
                for (int r = 0; r < 16; ++r) {
                    u32 b = __float_as_uint(v[r]);
                    if (b < thr && b > lm) lm = b;
                }
            }
            u32 m = wred_max(lm);
            u32 lc = 0u;
            if (m) {
#pragma unroll
                for (int r = 0; r < 16; ++r) lc += (__float_as_uint(v[r]) == m) ? 1u : 0u;
            }
            u32 c = wred_sum_u32(lc);
            if (lane == 0) { pairs1[wid][k][0] = m; pairs1[wid][k][1] = c; }
            need = (m == 0u) ? 0u : ((c >= need) ? 0u : need - c);
            thr = m;                 // m==0 -> thr=0 -> no further candidates
        }
    }
    __syncthreads();
    if (wid == 0) {
        u32 t, bn;
        merge_pairs(&pairs1[0][0][0], 4 * KTOP, KTOP, t, bn, lane);
        if (lane == 0) { s_v10 = t; s_bneed = bn; }
    }
    __syncthreads();
    u32 v10 = s_v10, bneed = s_bneed;

    // ---- votes + argmax (first-max tie-break == jnp.argmax) ----
#pragma unroll
    for (int r = 0; r < 16; ++r) {
        u32 b = __float_as_uint(v[r]);
        if (b > v10) atomicAdd(&votebin[LAB(r)], 1u);
        else if (b == v10) {
            u32 p = atomicAdd(&s_eqcnt, 1u);
            if (p < 64u) eqlist[p] = ((u32)(tid * 16 + r) << 8) | (u32)LAB(r);
        }
    }
    __syncthreads();
    if (tid == 0) {      // boundary: bneed smallest-idx elements at v == v10 vote
        int ne = (int)min(s_eqcnt, 64u);
        for (u32 k = 0; k < bneed; ++k) {
            u32 best = ~0u; int bi = -1;
            for (int e = 0; e < ne; ++e) if (eqlist[e] < best) { best = eqlist[e]; bi = e; }
            if (bi >= 0) { votebin[best & 0xFFu] += 1u; eqlist[bi] = ~0u; }
        }
    }
    __syncthreads();
    int asg;
    {
        u32 vk = (lane < NCLS) ? ((votebin[lane] << 6) | (u32)(63 - lane)) : 0u;
        vk = wred_max(vk);
        asg = 63 - (int)(vk & 63u);
    }

    // ---- phases 2/3: per-wave masked top-5 extraction (same / diff label) ----
    u32 sm16 = 0u;
#pragma unroll
    for (int r = 0; r < 16; ++r) if (LAB(r) == asg) sm16 |= 1u << r;
    {
        u32 thr = ~0u, need = MTOP;
#pragma unroll
        for (int k = 0; k < MTOP; ++k) {
            u32 lm = 0u;
            if (need) {
#pragma unroll
                for (int r = 0; r < 16; ++r) {
                    u32 b = __float_as_uint(v[r]);
                    if (((sm16 >> r) & 1u) && b < thr && b > lm) lm = b;
                }
            }
            u32 m = wred_max(lm);
            u32 lc = 0u;
            if (m) {
#pragma unroll
                for (int r = 0; r < 16; ++r)
                    lc += (((sm16 >> r) & 1u) && __float_as_uint(v[r]) == m) ? 1u : 0u;
            }
            u32 c = wred_sum_u32(lc);
            if (lane == 0) { pairs2[wid][k][0] = m; pairs2[wid][k][1] = c; }
            need = (m == 0u) ? 0u : ((c >= need) ? 0u : need - c);
            thr = m;
        }
    }
    {
        u32 thr = ~0u, need = MTOP;
#pragma unroll
        for (int k = 0; k < MTOP; ++k) {
            u32 lm = 0u;
            if (need) {
#pragma unroll
                for (int r = 0; r < 16; ++r) {
                    u32 b = __float_as_uint(v[r]);
                    if (!((sm16 >> r) & 1u) && b < thr && b > lm) lm = b;
                }
            }
            u32 m = wred_max(lm);
            u32 lc = 0u;
            if (m) {
#pragma unroll
                for (int r = 0; r < 16; ++r)
                    lc += (!((sm16 >> r) & 1u) && __float_as_uint(v[r]) == m) ? 1u : 0u;
            }
            u32 c = wred_sum_u32(lc);
            if (lane == 0) { pairs3[wid][k][0] = m; pairs3[wid][k][1] = c; }
            need = (m == 0u) ? 0u : ((c >= need) ? 0u : need - c);
            thr = m;
        }
    }
    __syncthreads();
    if (wid == 0) {
        u32 t, bn;
        merge_pairs(&pairs2[0][0][0], 4 * MTOP, MTOP, t, bn, lane);
        if (lane == 0) { s_t2 = t; s_b2 = bn; }
    }
    if (wid == 1) {
        u32 t, bn;
        merge_pairs(&pairs3[0][0][0], 4 * MTOP, MTOP, t, bn, lane);
        if (lane == 0) { s_t3 = t; s_b3 = bn; }
    }
    __syncthreads();
    u32 t2 = s_t2, b2 = s_b2, t3 = s_t3, b3 = s_b3;

    // ---- sums: strictly-greater + boundary-count * threshold (exact set) ----
    float s2 = 0.f, s3 = 0.f;
#pragma unroll
    for (int r = 0; r < 16; ++r) {
        u32 b = __float_as_uint(v[r]);
        if ((sm16 >> r) & 1u) { if (b > t2) s2 += v[r]; }
        else                  { if (b > t3) s3 += v[r]; }
    }
    s2 = wred_sumf(s2);
    s3 = wred_sumf(s3);
    if (lane == 0) { sred2[wid] = s2; sred3[wid] = s3; }
    __syncthreads();
    if (tid == 0) {
        float nln = sred2[0] + sred2[1] + sred2[2] + sred2[3] + (float)b2 * __uint_as_float(t2);
        float nun = sred3[0] + sred3[1] + sred3[2] + sred3[3] + (float)b3 * __uint_as_float(t3);
        assigned[j] = asg;
        score[j] = nln / nun;
    }
#undef LAB
}

// ---------------- kernel 4: exact top-MU radix select + flab + class hist ----
__global__ __launch_bounds__(1024) void select_kernel(const float* __restrict__ score,
                                                      const int* __restrict__ assigned,
                                                      int* __restrict__ top_tgt,
                                                      int* __restrict__ flab,
                                                      int* __restrict__ histg) {
    __shared__ u64 keys[NN];        // 32 KB
    __shared__ __attribute__((aligned(16))) u32 hist[256];
    __shared__ u64 s_prefix;
    __shared__ u32 s_rem;
    __shared__ int hcls[32];
    __shared__ int s_counter;
    int tid = threadIdx.x;
#pragma unroll
    for (int t = 0; t < 4; ++t) {
        int i = t * 1024 + tid;
        keys[i] = ((u64)__float_as_uint(score[i]) << 32) | (u64)(0xFFFFFFFFu - (u32)i);
    }
    if (tid == 0) { s_prefix = 0ull; s_rem = MUSEL; s_counter = 0; }
    if (tid < 32) hcls[tid] = 0;
    if (tid < 256) hist[tid] = 0u;
    __syncthreads();
    for (int pass = 0; pass < 8; ++pass) {
        int shift = 56 - pass * 8;
        u64 pref = s_prefix;
#pragma unroll
        for (int t = 0; t < 4; ++t) {
            u64 k = keys[t * 1024 + tid];
            bool match = (pass == 0) || ((k >> (shift + 8)) == (pref >> (shift + 8)));
            if (match) atomicAdd(&hist[(u32)(k >> shift) & 255u], 1u);
        }
        __syncthreads();
        if (tid < 64) {               // wave0 parallel pick (zeroes hist)
            int g = 63 - tid;
            uint4 h = *(uint4*)&hist[4 * g];
            *(uint4*)&hist[4 * g] = make_uint4(0u, 0u, 0u, 0u);
            u32 s = h.x + h.y + h.z + h.w, P = s;
#pragma unroll
            for (int o = 1; o < 64; o <<= 1) { u32 tt = __shfl_up(P, o); if (tid >= o) P += tt; }
            u32 need = s_rem;
            unsigned long long bal = __ballot(P >= need);   // nonzero by invariant
            int l0 = __ffsll(bal) - 1;
            u32 c = P - s, b, nn;
            if (c + h.w >= need) { b = 3u; nn = need - c; }
            else { c += h.w; if (c + h.z >= need) { b = 2u; nn = need - c; }
                   else { c += h.z; if (c + h.y >= need) { b = 1u; nn = need - c; }
                          else { c += h.y; b = 0u; nn = need - c; } } }
            if (tid == l0) { s_prefix = pref | ((u64)((u32)(4 * g) + b) << shift); s_rem = nn; }
        }
        __syncthreads();
    }
    u64 thr = s_prefix;   // exact MUSEL-th largest key
#pragma unroll
    for (int t = 0; t < 4; ++t) {
        int i = t * 1024 + tid;
        if (keys[i] >= thr) {
            int p = atomicAdd(&s_counter, 1);
            int idx = (int)(0xFFFFFFFFu - (u32)(keys[i] & 0xFFFFFFFFull));
            top_tgt[p] = idx;
            int a = assigned[idx];
            flab[p] = a;
            atomicAdd(&hcls[a], 1);
        }
    }
    __syncthreads();
    if (tid < 32) histg[tid] = hcls[tid];
}

// ---------------- kernel 6: softmax partial sums (no max shift needed) -------
// sim in (0,1] so exp(v) <= e: direct sums exact-equivalent to max-shifted.
#define JCH 64
__global__ __launch_bounds__(256) void fpart_kernel(const float* __restrict__ simT,
                                                    const int* __restrict__ top_tgt,
                                                    const int* __restrict__ flab,
                                                    const int* __restrict__ labels,
                                                    float* __restrict__ ps,
                                                    float* __restrict__ pt) {
    __shared__ int tt[JCH];
    __shared__ int fl[JCH];
    int tid = threadIdx.x;
    int ci = blockIdx.x, cj = blockIdx.y;
    if (tid < JCH) { tt[tid] = top_tgt[cj * JCH + tid]; fl[tid] = flab[cj * JCH + tid]; }
    __syncthreads();
    int i = ci * 256 + tid;
    int myl = labels[i];
    float s = 0.f, t = 0.f;
#pragma unroll 4
    for (int jj = 0; jj < JCH; ++jj) {
        float v = simT[(size_t)tt[jj] * NN + i];
        float e = __expf(v);
        s += e;
        t += (fl[jj] == myl) ? e : 0.f;
    }
    ps[cj * NN + i] = s;
    pt[cj * NN + i] = t;
}

// ---------------- kernel 7: merge partials -> per-block loss partials --------
__global__ __launch_bounds__(256) void merge_kernel(const float* __restrict__ ps,
                                                    const float* __restrict__ pt,
                                                    const int* __restrict__ labels,
                                                    const int* __restrict__ hist,
                                                    float* __restrict__ partials) {
    int tid = threadIdx.x;
    int i = blockIdx.x * 256 + tid;
    float S = 0.f, T = 0.f;
#pragma unroll
    for (int c = 0; c < 32; ++c) {
        S += ps[c * NN + i];
        T += pt[c * NN + i];
    }
    float contr = T / S;
    int ns = hist[labels[i]];
    bool valid = (ns > 0) && (ns < MUSEL);
    float term = valid ? __logf(contr) : 0.0f;
    float cnt = valid ? 1.0f : 0.0f;
    for (int off = 32; off > 0; off >>= 1) {
        term += __shfl_down(term, off);
        cnt  += __shfl_down(cnt, off);
    }
    __shared__ float rt[4], rc[4];
    int wid = tid >> 6, lane = tid & 63;
    if (lane == 0) { rt[wid] = term; rc[wid] = cnt; }
    __syncthreads();
    if (tid == 0) {
        partials[blockIdx.x * 2]     = rt[0] + rt[1] + rt[2] + rt[3];
        partials[blockIdx.x * 2 + 1] = rc[0] + rc[1] + rc[2] + rc[3];
    }
}

// ---------------- kernel 8: final scalar -------------------------------------
__global__ void final_kernel(const float* __restrict__ partials, float* __restrict__ out) {
    if (threadIdx.x == 0) {
        float s = 0.f, c = 0.f;
        for (int b = 0; b < 16; ++b) { s += partials[b * 2]; c += partials[b * 2 + 1]; }
        out[0] = -s / c;
    }
}

extern "C" void kernel_launch(void* const* d_in, const int* in_sizes, int n_in,
                              void* d_out, int out_size, void* d_ws, size_t ws_size,
                              hipStream_t stream) {
    const float* src    = (const float*)d_in[0];
    const int*   labels = (const int*)d_in[1];
    const float* tgt    = (const float*)d_in[2];
    float* out = (float*)d_out;

    char* ws = (char*)d_ws;
    size_t off = 0;
    float* simT = (float*)(ws + off);             off += (size_t)NN * NN * sizeof(float); // 64 MB
    unsigned short* tgt_hi = (unsigned short*)(ws + off); off += (size_t)NN * DD * 2;     // 2 MB
    unsigned short* tgt_lo = (unsigned short*)(ws + off); off += (size_t)NN * DD * 2;
    unsigned short* src_hi = (unsigned short*)(ws + off); off += (size_t)NN * DD * 2;
    unsigned short* src_lo = (unsigned short*)(ws + off); off += (size_t)NN * DD * 2;
    float* sq_s = (float*)(ws + off);      off += NN * sizeof(float);
    float* sq_t = (float*)(ws + off);      off += NN * sizeof(float);
    float* score = (float*)(ws + off);     off += NN * sizeof(float);
    int*   assigned = (int*)(ws + off);    off += NN * sizeof(int);
    int*   top_tgt = (int*)(ws + off);     off += MUSEL * sizeof(int);
    int*   flab = (int*)(ws + off);        off += MUSEL * sizeof(int);
    int*   hist = (int*)(ws + off);        off += 32 * sizeof(int);
    float* partials = (float*)(ws + off);  off += 32 * sizeof(float);
    // ps/pt (512 KB each) alias the dead-after-GEMM bf16 planes (2 MB each)
    float* ps = (float*)tgt_lo;
    float* pt = (float*)src_hi;

    prep_kernel<<<2 * NN, 256, 0, stream>>>(src, tgt, src_hi, src_lo, tgt_hi, tgt_lo, sq_s, sq_t);
    gemm_mfma_kernel<<<1024, 256, 0, stream>>>(tgt_hi, tgt_lo, src_hi, src_lo, sq_s, sq_t, simT);
    percol_kernel<<<NN, 256, 0, stream>>>(simT, labels, assigned, score);
    select_kernel<<<1, 1024, 0, stream>>>(score, assigned, top_tgt, flab, hist);
    fpart_kernel<<<dim3(16, 32), 256, 0, stream>>>(simT, top_tgt, flab, labels, ps, pt);
    merge_kernel<<<16, 256, 0, stream>>>(ps, pt, labels, hist, partials);
    final_kernel<<<1, 64, 0, stream>>>(partials, out);
}

// Round 11
// 172.606 us; speedup vs baseline: 1.2115x; 1.2115x over previous
//
#include <hip/hip_runtime.h>
#include <hip/hip_bf16.h>
#include <cfloat>

#define NN 4096
#define DD 256
#define KTOP 10
#define MTOP 5
#define MUSEL 2048
#define NCLS 31

typedef unsigned long long u64;
typedef unsigned int u32;
typedef __attribute__((ext_vector_type(8))) short short8;   // 8 bf16 (4 VGPRs)
typedef __attribute__((ext_vector_type(4))) float f32x4;    // MFMA acc

static __device__ __forceinline__ unsigned short f2bf(float x) {
    u32 u = __float_as_uint(x);
    u32 r = (u + 0x7FFFu + ((u >> 16) & 1u)) >> 16;   // RNE, no NaN inputs here
    return (unsigned short)r;
}
static __device__ __forceinline__ float bf2f(unsigned short h) {
    return __uint_as_float((u32)h << 16);
}

// ---- DPP wave reductions (validated on HW rounds 4/9/10, absmax 0) ----------
template <int C>
static __device__ __forceinline__ u32 dpp_keep(u32 x) {   // invalid lanes keep old
    return (u32)__builtin_amdgcn_update_dpp((int)x, (int)x, C, 0xF, 0xF, false);
}
template <int C>
static __device__ __forceinline__ u32 dpp_zero(u32 x) {   // invalid lanes -> 0
    return (u32)__builtin_amdgcn_update_dpp(0, (int)x, C, 0xF, 0xF, true);
}
static __device__ __forceinline__ u32 wred_max(u32 x) {
#define S(C) { u32 t = dpp_keep<C>(x); x = t > x ? t : x; }
    S(0x111) S(0x112) S(0x114) S(0x118) S(0x142) S(0x143)
#undef S
    return (u32)__builtin_amdgcn_readlane((int)x, 63);
}
static __device__ __forceinline__ u32 wred_sum_u32(u32 x) {
#define S(C) { u32 t = dpp_zero<C>(x); x += t; }
    S(0x111) S(0x112) S(0x114) S(0x118) S(0x142) S(0x143)
#undef S
    return (u32)__builtin_amdgcn_readlane((int)x, 63);
}
static __device__ __forceinline__ float wred_sumf(float x) {
#define S(C) { u32 t = dpp_zero<C>(__float_as_uint(x)); x += __uint_as_float(t); }
    S(0x111) S(0x112) S(0x114) S(0x118) S(0x142) S(0x143)
#undef S
    return __uint_as_float((u32)__builtin_amdgcn_readlane((int)__float_as_uint(x), 63));
}

// ---- merge (value,count) pairs from LDS (duplicate-value entries summed) ----
static __device__ __forceinline__ void merge_pairs(const u32* pairs, int n, u32 need,
                                                   u32& t, u32& bn, int lane) {
    u32 val = (lane < n) ? pairs[lane * 2] : 0u;
    u32 cnt = (lane < n) ? pairs[lane * 2 + 1] : 0u;
    t = 0u; bn = 0u;
    for (int k = 0; k < 10; ++k) {
        if (need == 0u) break;                 // wave-uniform
        u32 m = wred_max(val);
        if (m == 0u) break;                    // exhausted -> take-all semantics
        u32 c = wred_sum_u32(val == m ? cnt : 0u);
        if (c >= need) { t = m; bn = need; break; }
        need -= c;
        if (val == m) val = 0u;
    }
}

// ---------------- kernel 0: fused fp32->bf16 hi/lo planes + row sq norms -----
__global__ __launch_bounds__(256) void prep_kernel(const float* __restrict__ src,
                                                   const float* __restrict__ tgt,
                                                   unsigned short* __restrict__ src_hi,
                                                   unsigned short* __restrict__ src_lo,
                                                   unsigned short* __restrict__ tgt_hi,
                                                   unsigned short* __restrict__ tgt_lo,
                                                   float* __restrict__ sq_s,
                                                   float* __restrict__ sq_t) {
    int r = blockIdx.x;                      // 0..2N-1
    bool isT = r >= NN;
    int rr = isT ? r - NN : r;
    const float* base = (isT ? tgt : src) + (size_t)rr * DD;
    float x = base[threadIdx.x];
    unsigned short h = f2bf(x);
    unsigned short l = f2bf(x - bf2f(h));
    size_t o = (size_t)rr * DD + threadIdx.x;
    if (isT) { tgt_hi[o] = h; tgt_lo[o] = l; } else { src_hi[o] = h; src_lo[o] = l; }
    float p = x * x;
    for (int off = 32; off > 0; off >>= 1) p += __shfl_down(p, off);
    __shared__ float red[4];
    int wid = threadIdx.x >> 6, lane = threadIdx.x & 63;
    if (lane == 0) red[wid] = p;
    __syncthreads();
    if (threadIdx.x == 0) {
        float s = red[0] + red[1] + red[2] + red[3];
        if (isT) sq_t[rr] = s; else sq_s[rr] = s;
    }
}

// ---------------- kernel 2: bf16 MFMA GEMM, 4-plane staging (r9 version) -----
// dot = hiT.hiS + hiT.loS + loT.hiS. Stage all 4 unique planes once per 32-wide
// K-slice; 48 MFMAs per barrier pair; 32KB LDS keeps 4-5 blocks/CU (dbuf at
// 64KB cost 14us in r10 -- occupancy is the hiding mechanism, reverted).
static __device__ __forceinline__ void gload(const unsigned short* g, short* l) {
    __builtin_amdgcn_global_load_lds((const __attribute__((address_space(1))) void*)g,
                                     (__attribute__((address_space(3))) void*)l, 16, 0, 0);
}

__global__ __launch_bounds__(256) void gemm_mfma_kernel(
        const unsigned short* __restrict__ tgt_hi, const unsigned short* __restrict__ tgt_lo,
        const unsigned short* __restrict__ src_hi, const unsigned short* __restrict__ src_lo,
        const float* __restrict__ sq_s, const float* __restrict__ sq_t,
        float* __restrict__ simT) {
    __shared__ short Ahi[128 * 32];   // tgt_hi tile [row j'][k], 64B rows
    __shared__ short Alo[128 * 32];
    __shared__ short Bhi[128 * 32];   // src_hi tile [row i'][k]
    __shared__ short Blo[128 * 32];
    int tid = threadIdx.x;
    int wid = tid >> 6, lane = tid & 63;
    // bijective XCD swizzle (1024 blocks % 8 == 0)
    int lin = blockIdx.x;
    int wg = (lin & 7) * 128 + (lin >> 3);
    int i0 = (wg & 31) * 128;
    int j0 = (wg >> 5) * 128;
    int wr = wid >> 1, wc = wid & 1;

    f32x4 acc[4][4];
#pragma unroll
    for (int m = 0; m < 4; ++m)
#pragma unroll
        for (int n = 0; n < 4; ++n) acc[m][n] = (f32x4){0.f, 0.f, 0.f, 0.f};

    int srow = wid * 32 + (lane >> 2);    // wave covers tile rows [wid*32, wid*32+32)
    int skoff = (lane & 3) * 8;
    int fr = lane & 15;
    int kq = (lane >> 4) * 8;

    for (int t = 0; t < 8; ++t) {
        int kk = t * 32;
#pragma unroll
        for (int r = 0; r < 2; ++r) {
            int row = srow + r * 16;
            size_t goA = (size_t)(j0 + row) * DD + kk + skoff;
            size_t goB = (size_t)(i0 + row) * DD + kk + skoff;
            int ldo = (wid * 2 + r) * 512;     // wave-uniform LDS chunk base
            gload(tgt_hi + goA, Ahi + ldo);
            gload(tgt_lo + goA, Alo + ldo);
            gload(src_hi + goB, Bhi + ldo);
            gload(src_lo + goB, Blo + ldo);
        }
        __syncthreads();                       // drains vmcnt: planes ready
        short8 ah[4], bh[4], bl[4], al[4];
#pragma unroll
        for (int m = 0; m < 4; ++m) {
            int ra = (wr * 64 + m * 16 + fr) * 32 + kq;
            int rb = (wc * 64 + m * 16 + fr) * 32 + kq;
            ah[m] = *(const short8*)(Ahi + ra);
            bh[m] = *(const short8*)(Bhi + rb);
        }
#pragma unroll
        for (int m = 0; m < 4; ++m)
#pragma unroll
            for (int n = 0; n < 4; ++n)
                acc[m][n] = __builtin_amdgcn_mfma_f32_16x16x32_bf16(ah[m], bh[n], acc[m][n], 0, 0, 0);
#pragma unroll
        for (int m = 0; m < 4; ++m)
            bl[m] = *(const short8*)(Blo + (wc * 64 + m * 16 + fr) * 32 + kq);
#pragma unroll
        for (int m = 0; m < 4; ++m)
#pragma unroll
            for (int n = 0; n < 4; ++n)
                acc[m][n] = __builtin_amdgcn_mfma_f32_16x16x32_bf16(ah[m], bl[n], acc[m][n], 0, 0, 0);
#pragma unroll
        for (int m = 0; m < 4; ++m)
            al[m] = *(const short8*)(Alo + (wr * 64 + m * 16 + fr) * 32 + kq);
#pragma unroll
        for (int m = 0; m < 4; ++m)
#pragma unroll
            for (int n = 0; n < 4; ++n)
                acc[m][n] = __builtin_amdgcn_mfma_f32_16x16x32_bf16(al[m], bh[n], acc[m][n], 0, 0, 0);
        __syncthreads();                       // protect LDS reuse
    }

    int fq = lane >> 4;
#pragma unroll
    for (int m = 0; m < 4; ++m) {
#pragma unroll
        for (int n = 0; n < 4; ++n) {
            int i = i0 + wc * 64 + n * 16 + fr;
            float ss = sq_s[i];
#pragma unroll
            for (int r = 0; r < 4; ++r) {
                int j = j0 + wr * 64 + m * 16 + fq * 4 + r;
                float d2 = fmaxf(ss + sq_t[j] - 2.0f * acc[m][n][r], 0.0f);
                simT[(size_t)j * NN + i] = 1.0f / (sqrtf(d2) + 1.0f);
            }
        }
    }
}

// ---------------- kernel 3: percol via sorted-lane shift-merge extraction ----
// Each lane bitonic-sorts its 16 values descending (one-time, ~160 VALU ops);
// extraction rounds are then wred_max(heads) + ballot + exec-masked shift --
// no per-round rescans or count loops. Duplicate values repeat across rounds;
// merge_pairs sums duplicate-value entries, so block thresholds + boundary
// counts are exact (identical semantics to verified r10 path).
#define CED(X,Y) { u32 mx_ = X > Y ? X : Y; u32 mn_ = X > Y ? Y : X; X = mx_; Y = mn_; }
#define CEA(X,Y) { u32 mx_ = X > Y ? X : Y; u32 mn_ = X > Y ? Y : X; X = mn_; Y = mx_; }
#define SORT16_DESC()                                                                         \
    CED(a0,a1) CEA(a2,a3) CED(a4,a5) CEA(a6,a7) CED(a8,a9) CEA(a10,a11) CED(a12,a13) CEA(a14,a15) \
    CED(a0,a2) CED(a1,a3) CEA(a4,a6) CEA(a5,a7) CED(a8,a10) CED(a9,a11) CEA(a12,a14) CEA(a13,a15) \
    CED(a0,a1) CED(a2,a3) CEA(a4,a5) CEA(a6,a7) CED(a8,a9) CED(a10,a11) CEA(a12,a13) CEA(a14,a15) \
    CED(a0,a4) CED(a1,a5) CED(a2,a6) CED(a3,a7) CEA(a8,a12) CEA(a9,a13) CEA(a10,a14) CEA(a11,a15) \
    CED(a0,a2) CED(a1,a3) CED(a4,a6) CED(a5,a7) CEA(a8,a10) CEA(a9,a11) CEA(a12,a14) CEA(a13,a15) \
    CED(a0,a1) CED(a2,a3) CED(a4,a5) CED(a6,a7) CEA(a8,a9) CEA(a10,a11) CEA(a12,a13) CEA(a14,a15) \
    CED(a0,a8) CED(a1,a9) CED(a2,a10) CED(a3,a11) CED(a4,a12) CED(a5,a13) CED(a6,a14) CED(a7,a15) \
    CED(a0,a4) CED(a1,a5) CED(a2,a6) CED(a3,a7) CED(a8,a12) CED(a9,a13) CED(a10,a14) CED(a11,a15) \
    CED(a0,a2) CED(a1,a3) CED(a4,a6) CED(a5,a7) CED(a8,a10) CED(a9,a11) CED(a12,a14) CED(a13,a15) \
    CED(a0,a1) CED(a2,a3) CED(a4,a5) CED(a6,a7) CED(a8,a9) CED(a10,a11) CED(a12,a13) CED(a14,a15)
#define SHIFT15() { a0=a1;a1=a2;a2=a3;a3=a4;a4=a5;a5=a6;a6=a7;a7=a8;a8=a9;a9=a10;a10=a11;a11=a12;a12=a13;a13=a14;a14=a15;a15=0u; }
#define SETA(F) { a0=F(0);a1=F(1);a2=F(2);a3=F(3);a4=F(4);a5=F(5);a6=F(6);a7=F(7); \
                  a8=F(8);a9=F(9);a10=F(10);a11=F(11);a12=F(12);a13=F(13);a14=F(14);a15=F(15); }
#define EXTRACT(PAIRS, NEEDK, ROUNDS)                                     \
    {                                                                     \
        u32 need_ = NEEDK;                                                \
        for (int k_ = 0; k_ < ROUNDS; ++k_) {                             \
            u32 m_ = wred_max(a0);                                        \
            if (m_ == 0u) break;                                          \
            unsigned long long bal_ = __ballot(a0 == m_);                 \
            u32 c_ = (u32)__popcll(bal_);                                 \
            if (lane == 0) { PAIRS[k_][0] = m_; PAIRS[k_][1] = c_; }      \
            if (a0 == m_) SHIFT15()                                       \
            if (c_ >= need_) break;                                       \
            need_ -= c_;                                                  \
        }                                                                 \
    }

__global__ __launch_bounds__(256) void percol_kernel(const float* __restrict__ simT,
                                                     const int* __restrict__ labels,
                                                     int* __restrict__ assigned,
                                                     float* __restrict__ score) {
    __shared__ u32 pairs1[4][KTOP][2];
    __shared__ u32 pairs2[4][MTOP][2];
    __shared__ u32 pairs3[4][MTOP][2];
    __shared__ u32 votebin[32];
    __shared__ u32 eqlist[64];
    __shared__ u32 s_eqcnt;
    __shared__ u32 s_v10, s_bneed;
    __shared__ u32 s_t2, s_b2, s_t3, s_b3;
    __shared__ float sred2[4], sred3[4];
    int tid = threadIdx.x, lane = tid & 63, wid = tid >> 6;
    int j = blockIdx.x;

    float v[16];
    u32 labp[4];
    {
        const float4* pA = (const float4*)(simT + (size_t)j * NN + tid * 16);
        const int4*  pL = (const int4*)(labels + tid * 16);
#pragma unroll
        for (int q = 0; q < 4; ++q) {
            float4 a = pA[q];
            v[q * 4 + 0] = a.x; v[q * 4 + 1] = a.y; v[q * 4 + 2] = a.z; v[q * 4 + 3] = a.w;
            int4 l = pL[q];
            labp[q] = (u32)l.x | ((u32)l.y << 8) | ((u32)l.z << 16) | ((u32)l.w << 24);
        }
    }
#define LAB(r) ((int)((labp[(r) >> 2] >> (((r) & 3) * 8)) & 0xFFu))
    if (tid < 32) votebin[tid] = 0u;
    if (tid == 0) s_eqcnt = 0u;
    // each wave zeroes its OWN pair slots (wave-ordered with its later writes)
    if (lane < KTOP) { pairs1[wid][lane][0] = 0u; pairs1[wid][lane][1] = 0u; }
    if (lane < MTOP) {
        pairs2[wid][lane][0] = 0u; pairs2[wid][lane][1] = 0u;
        pairs3[wid][lane][0] = 0u; pairs3[wid][lane][1] = 0u;
    }

    u32 a0, a1, a2, a3, a4, a5, a6, a7, a8, a9, a10, a11, a12, a13, a14, a15;

    // ---- phase 1: per-wave top-10 extraction over sorted lanes ----
#define BITS(r) __float_as_uint(v[r])
    SETA(BITS)
    SORT16_DESC()
    EXTRACT(pairs1[wid], KTOP, KTOP)
    __syncthreads();
    if (wid == 0) {
        u32 t, bn;
        merge_pairs(&pairs1[0][0][0], 4 * KTOP, KTOP, t, bn, lane);
        if (lane == 0) { s_v10 = t; s_bneed = bn; }
    }
    __syncthreads();
    u32 v10 = s_v10, bneed = s_bneed;

    // ---- votes + argmax (first-max tie-break == jnp.argmax) ----
#pragma unroll
    for (int r = 0; r < 16; ++r) {
        u32 b = __float_as_uint(v[r]);
        if (b > v10) atomicAdd(&votebin[LAB(r)], 1u);
        else if (b == v10) {
            u32 p = atomicAdd(&s_eqcnt, 1u);
            if (p < 64u) eqlist[p] = ((u32)(tid * 16 + r) << 8) | (u32)LAB(r);
        }
    }
    __syncthreads();
    if (tid == 0) {      // boundary: bneed smallest-idx elements at v == v10 vote
        int ne = (int)min(s_eqcnt, 64u);
        for (u32 k = 0; k < bneed; ++k) {
            u32 best = ~0u; int bi = -1;
            for (int e = 0; e < ne; ++e) if (eqlist[e] < best) { best = eqlist[e]; bi = e; }
            if (bi >= 0) { votebin[best & 0xFFu] += 1u; eqlist[bi] = ~0u; }
        }
    }
    __syncthreads();
    int asg;
    {
        u32 vk = (lane < NCLS) ? ((votebin[lane] << 6) | (u32)(63 - lane)) : 0u;
        vk = wred_max(vk);
        asg = 63 - (int)(vk & 63u);
    }

    // ---- phases 2/3: masked sorted extraction (same / diff label) ----
    u32 sm16 = 0u;
#pragma unroll
    for (int r = 0; r < 16; ++r) if (LAB(r) == asg) sm16 |= 1u << r;

#define BITS2(r) ((((sm16 >> (r)) & 1u)) ? __float_as_uint(v[r]) : 0u)
    SETA(BITS2)
    SORT16_DESC()
    EXTRACT(pairs2[wid], MTOP, MTOP)

#define BITS3(r) ((((sm16 >> (r)) & 1u)) ? 0u : __float_as_uint(v[r]))
    SETA(BITS3)
    SORT16_DESC()
    EXTRACT(pairs3[wid], MTOP, MTOP)

    __syncthreads();
    if (wid == 0) {
        u32 t, bn;
        merge_pairs(&pairs2[0][0][0], 4 * MTOP, MTOP, t, bn, lane);
        if (lane == 0) { s_t2 = t; s_b2 = bn; }
    }
    if (wid == 1) {
        u32 t, bn;
        merge_pairs(&pairs3[0][0][0], 4 * MTOP, MTOP, t, bn, lane);
        if (lane == 0) { s_t3 = t; s_b3 = bn; }
    }
    __syncthreads();
    u32 t2 = s_t2, b2 = s_b2, t3 = s_t3, b3 = s_b3;

    // ---- sums: strictly-greater + boundary-count * threshold (exact set) ----
    float s2 = 0.f, s3 = 0.f;
#pragma unroll
    for (int r = 0; r < 16; ++r) {
        u32 b = __float_as_uint(v[r]);
        if ((sm16 >> r) & 1u) { if (b > t2) s2 += v[r]; }
        else                  { if (b > t3) s3 += v[r]; }
    }
    s2 = wred_sumf(s2);
    s3 = wred_sumf(s3);
    if (lane == 0) { sred2[wid] = s2; sred3[wid] = s3; }
    __syncthreads();
    if (tid == 0) {
        float nln = sred2[0] + sred2[1] + sred2[2] + sred2[3] + (float)b2 * __uint_as_float(t2);
        float nun = sred3[0] + sred3[1] + sred3[2] + sred3[3] + (float)b3 * __uint_as_float(t3);
        assigned[j] = asg;
        score[j] = nln / nun;
    }
#undef LAB
#undef BITS
#undef BITS2
#undef BITS3
}

// ---------------- kernel 4: exact top-MU radix select + flab + class hist ----
__global__ __launch_bounds__(1024) void select_kernel(const float* __restrict__ score,
                                                      const int* __restrict__ assigned,
                                                      int* __restrict__ top_tgt,
                                                      int* __restrict__ flab,
                                                      int* __restrict__ histg) {
    __shared__ u64 keys[NN];        // 32 KB
    __shared__ __attribute__((aligned(16))) u32 hist[256];
    __shared__ u64 s_prefix;
    __shared__ u32 s_rem;
    __shared__ int hcls[32];
    __shared__ int s_counter;
    int tid = threadIdx.x;
#pragma unroll
    for (int t = 0; t < 4; ++t) {
        int i = t * 1024 + tid;
        keys[i] = ((u64)__float_as_uint(score[i]) << 32) | (u64)(0xFFFFFFFFu - (u32)i);
    }
    if (tid == 0) { s_prefix = 0ull; s_rem = MUSEL; s_counter = 0; }
    if (tid < 32) hcls[tid] = 0;
    if (tid < 256) hist[tid] = 0u;
    __syncthreads();
    for (int pass = 0; pass < 8; ++pass) {
        int shift = 56 - pass * 8;
        u64 pref = s_prefix;
#pragma unroll
        for (int t = 0; t < 4; ++t) {
            u64 k = keys[t * 1024 + tid];
            bool match = (pass == 0) || ((k >> (shift + 8)) == (pref >> (shift + 8)));
            if (match) atomicAdd(&hist[(u32)(k >> shift) & 255u], 1u);
        }
        __syncthreads();
        if (tid < 64) {               // wave0 parallel pick (zeroes hist)
            int g = 63 - tid;
            uint4 h = *(uint4*)&hist[4 * g];
            *(uint4*)&hist[4 * g] = make_uint4(0u, 0u, 0u, 0u);
            u32 s = h.x + h.y + h.z + h.w, P = s;
#pragma unroll
            for (int o = 1; o < 64; o <<= 1) { u32 tt = __shfl_up(P, o); if (tid >= o) P += tt; }
            u32 need = s_rem;
            unsigned long long bal = __ballot(P >= need);   // nonzero by invariant
            int l0 = __ffsll(bal) - 1;
            u32 c = P - s, b, nn;
            if (c + h.w >= need) { b = 3u; nn = need - c; }
            else { c += h.w; if (c + h.z >= need) { b = 2u; nn = need - c; }
                   else { c += h.z; if (c + h.y >= need) { b = 1u; nn = need - c; }
                          else { c += h.y; b = 0u; nn = need - c; } } }
            if (tid == l0) { s_prefix = pref | ((u64)((u32)(4 * g) + b) << shift); s_rem = nn; }
        }
        __syncthreads();
    }
    u64 thr = s_prefix;   // exact MUSEL-th largest key
#pragma unroll
    for (int t = 0; t < 4; ++t) {
        int i = t * 1024 + tid;
        if (keys[i] >= thr) {
            int p = atomicAdd(&s_counter, 1);
            int idx = (int)(0xFFFFFFFFu - (u32)(keys[i] & 0xFFFFFFFFull));
            top_tgt[p] = idx;
            int a = assigned[idx];
            flab[p] = a;
            atomicAdd(&hcls[a], 1);
        }
    }
    __syncthreads();
    if (tid < 32) histg[tid] = hcls[tid];
}

// ---------------- kernel 6: softmax partial sums (no max shift needed) -------
// sim in (0,1] so exp(v) <= e: direct sums exact-equivalent to max-shifted.
#define JCH 64
__global__ __launch_bounds__(256) void fpart_kernel(const float* __restrict__ simT,
                                                    const int* __restrict__ top_tgt,
                                                    const int* __restrict__ flab,
                                                    const int* __restrict__ labels,
                                                    float* __restrict__ ps,
                                                    float* __restrict__ pt) {
    __shared__ int tt[JCH];
    __shared__ int fl[JCH];
    int tid = threadIdx.x;
    int ci = blockIdx.x, cj = blockIdx.y;
    if (tid < JCH) { tt[tid] = top_tgt[cj * JCH + tid]; fl[tid] = flab[cj * JCH + tid]; }
    __syncthreads();
    int i = ci * 256 + tid;
    int myl = labels[i];
    float s = 0.f, t = 0.f;
#pragma unroll 4
    for (int jj = 0; jj < JCH; ++jj) {
        float v = simT[(size_t)tt[jj] * NN + i];
        float e = __expf(v);
        s += e;
        t += (fl[jj] == myl) ? e : 0.f;
    }
    ps[cj * NN + i] = s;
    pt[cj * NN + i] = t;
}

// ---------------- kernel 7: merge partials -> per-block loss partials --------
__global__ __launch_bounds__(256) void merge_kernel(const float* __restrict__ ps,
                                                    const float* __restrict__ pt,
                                                    const int* __restrict__ labels,
                                                    const int* __restrict__ hist,
                                                    float* __restrict__ partials) {
    int tid = threadIdx.x;
    int i = blockIdx.x * 256 + tid;
    float S = 0.f, T = 0.f;
#pragma unroll
    for (int c = 0; c < 32; ++c) {
        S += ps[c * NN + i];
        T += pt[c * NN + i];
    }
    float contr = T / S;
    int ns = hist[labels[i]];
    bool valid = (ns > 0) && (ns < MUSEL);
    float term = valid ? __logf(contr) : 0.0f;
    float cnt = valid ? 1.0f : 0.0f;
    for (int off = 32; off > 0; off >>= 1) {
        term += __shfl_down(term, off);
        cnt  += __shfl_down(cnt, off);
    }
    __shared__ float rt[4], rc[4];
    int wid = tid >> 6, lane = tid & 63;
    if (lane == 0) { rt[wid] = term; rc[wid] = cnt; }
    __syncthreads();
    if (tid == 0) {
        partials[blockIdx.x * 2]     = rt[0] + rt[1] + rt[2] + rt[3];
        partials[blockIdx.x * 2 + 1] = rc[0] + rc[1] + rc[2] + rc[3];
    }
}

// ---------------- kernel 8: final scalar -------------------------------------
__global__ void final_kernel(const float* __restrict__ partials, float* __restrict__ out) {
    if (threadIdx.x == 0) {
        float s = 0.f, c = 0.f;
        for (int b = 0; b < 16; ++b) { s += partials[b * 2]; c += partials[b * 2 + 1]; }
        out[0] = -s / c;
    }
}

extern "C" void kernel_launch(void* const* d_in, const int* in_sizes, int n_in,
                              void* d_out, int out_size, void* d_ws, size_t ws_size,
                              hipStream_t stream) {
    const float* src    = (const float*)d_in[0];
    const int*   labels = (const int*)d_in[1];
    const float* tgt    = (const float*)d_in[2];
    float* out = (float*)d_out;

    char* ws = (char*)d_ws;
    size_t off = 0;
    float* simT = (float*)(ws + off);             off += (size_t)NN * NN * sizeof(float); // 64 MB
    unsigned short* tgt_hi = (unsigned short*)(ws + off); off += (size_t)NN * DD * 2;     // 2 MB
    unsigned short* tgt_lo = (unsigned short*)(ws + off); off += (size_t)NN * DD * 2;
    unsigned short* src_hi = (unsigned short*)(ws + off); off += (size_t)NN * DD * 2;
    unsigned short* src_lo = (unsigned short*)(ws + off); off += (size_t)NN * DD * 2;
    float* sq_s = (float*)(ws + off);      off += NN * sizeof(float);
    float* sq_t = (float*)(ws + off);      off += NN * sizeof(float);
    float* score = (float*)(ws + off);     off += NN * sizeof(float);
    int*   assigned = (int*)(ws + off);    off += NN * sizeof(int);
    int*   top_tgt = (int*)(ws + off);     off += MUSEL * sizeof(int);
    int*   flab = (int*)(ws + off);        off += MUSEL * sizeof(int);
    int*   hist = (int*)(ws + off);        off += 32 * sizeof(int);
    float* partials = (float*)(ws + off);  off += 32 * sizeof(float);
    // ps/pt (512 KB each) alias the dead-after-GEMM bf16 planes (2 MB each)
    float* ps = (float*)tgt_lo;
    float* pt = (float*)src_hi;

    prep_kernel<<<2 * NN, 256, 0, stream>>>(src, tgt, src_hi, src_lo, tgt_hi, tgt_lo, sq_s, sq_t);
    gemm_mfma_kernel<<<1024, 256, 0, stream>>>(tgt_hi, tgt_lo, src_hi, src_lo, sq_s, sq_t, simT);
    percol_kernel<<<NN, 256, 0, stream>>>(simT, labels, assigned, score);
    select_kernel<<<1, 1024, 0, stream>>>(score, assigned, top_tgt, flab, hist);
    fpart_kernel<<<dim3(16, 32), 256, 0, stream>>>(simT, top_tgt, flab, labels, ps, pt);
    merge_kernel<<<16, 256, 0, stream>>>(ps, pt, labels, hist, partials);
    final_kernel<<<1, 64, 0, stream>>>(partials, out);
}